// Round 7
// baseline (331.906 us; speedup 1.0000x reference)
//
#include <hip/hip_runtime.h>

// SIZE=65536 nodes, MAX_EDGES=16777216.
// out[i] = bias[i] + sum over edges e with dst[e]==i of x[src[e]]*w[e].
//
// R1: global fp32 atomics ~20.6 G/s -> LDS histograms + private ws copies.
// R4: RANGES=2 (128KB LDS) guarded single-kernel: 140us, VGPR=20 ->
//     compiler sinks each guarded gather into its branch: serialized
//     L2 round-trip per edge. R6 sched_barrier(0) could not prevent it.
// R5: unguarded gathers DO batch (VGPR=44) but doubled active-lane work
//     on TA/LDS pipes (all lanes dummy-work) -> regressed.
// R7: two-phase. Phase A: unguarded full-lane gather v=x[src]*w (each
//     edge once, batched loads). Phase B: stream dst+v, guarded
//     fire-and-forget ds_add (no gather chain at all).

#define NNODES  65536
#define NEDGES  16777216
#define RANGES  2
#define BINS    (NNODES / RANGES)   // 32768 bins -> 128 KB dynamic LDS
#define THREADS 1024
#define NCOPIES 128                 // private output copies (32 MB)
#define GROUPS  16
#define CPG     (NCOPIES / GROUPS)
#define GBLOCKS 256                 // phase-A blocks

// ---------------- Phase A: v[e] = x[src[e]] * w[e], all lanes ----------------
__global__ __launch_bounds__(THREADS) void gather_kernel(
    const float* __restrict__ x,
    const float* __restrict__ w,
    const int*   __restrict__ src,
    float*       __restrict__ v)
{
    const int4*   src4 = (const int4*)src;
    const float4* wgt4 = (const float4*)w;
    float4*       v4   = (float4*)v;

    const int n8     = NEDGES / 8;
    const int stride = GBLOCKS * THREADS;

    for (int g = blockIdx.x * THREADS + (int)threadIdx.x; g < n8; g += stride) {
        int4   sa = src4[2 * g], sb = src4[2 * g + 1];
        float4 wa = wgt4[2 * g], wb = wgt4[2 * g + 1];

        // 8 unguarded gathers, straight-line -> batched under one vmcnt.
        float x0 = x[sa.x], x1 = x[sa.y], x2 = x[sa.z], x3 = x[sa.w];
        float x4_ = x[sb.x], x5 = x[sb.y], x6 = x[sb.z], x7 = x[sb.w];

        float4 va = { x0 * wa.x, x1 * wa.y, x2 * wa.z, x3 * wa.w };
        float4 vb = { x4_ * wb.x, x5 * wb.y, x6 * wb.z, x7 * wb.w };
        v4[2 * g]     = va;
        v4[2 * g + 1] = vb;
    }
}

// ---------------- Phase B: LDS hist from (dst, v) streams ----------------
// Block b: range r = b&1, chunk c = b>>1. No gathers: one vmcnt wait per
// iteration for the coalesced quads, then fire-and-forget guarded ds_adds.
__global__ __launch_bounds__(THREADS, 4) void scatter_kernel(
    const int*   __restrict__ dst,
    const float* __restrict__ v,
    float*       __restrict__ ws,   // copies base
    int B)
{
    extern __shared__ float h[];   // BINS floats = 128 KB

    const int b  = blockIdx.x;
    const int r  = b & (RANGES - 1);
    const int c  = b >> 1;
    const int lo = r * BINS;

    for (int i = threadIdx.x; i < BINS; i += THREADS) h[i] = 0.0f;
    __syncthreads();

    const int4*   dst4 = (const int4*)dst;
    const float4* val4 = (const float4*)v;

    const int n8 = NEDGES / 8;
    for (int g = c * THREADS + (int)threadIdx.x; g < n8; g += B * THREADS) {
        int4   da = dst4[2 * g], db = dst4[2 * g + 1];
        float4 va = val4[2 * g], vb = val4[2 * g + 1];

        unsigned bin[8] = {
            (unsigned)(da.x - lo), (unsigned)(da.y - lo),
            (unsigned)(da.z - lo), (unsigned)(da.w - lo),
            (unsigned)(db.x - lo), (unsigned)(db.y - lo),
            (unsigned)(db.z - lo), (unsigned)(db.w - lo) };
        float vv[8] = { va.x, va.y, va.z, va.w, vb.x, vb.y, vb.z, vb.w };

        #pragma unroll
        for (int k = 0; k < 8; ++k) {
            if (bin[k] < (unsigned)BINS) atomicAdd(&h[bin[k]], vv[k]);
        }
    }
    __syncthreads();

    float4* outc4 = (float4*)(ws + (size_t)c * NNODES + lo);
    const float4* h4 = (const float4*)h;
    for (int i = threadIdx.x; i < BINS / 4; i += THREADS) outc4[i] = h4[i];
}

// ------- Fallback single-kernel hist (R4 structure, ws < 96 MB) -------
__global__ __launch_bounds__(THREADS, 4) void hist_kernel(
    const float* __restrict__ x,
    const float* __restrict__ w,
    const int*   __restrict__ src,
    const int*   __restrict__ dst,
    float*       __restrict__ ws,
    int B)
{
    extern __shared__ float h[];

    const int b  = blockIdx.x;
    const int r  = b & (RANGES - 1);
    const int c  = b >> 1;
    const int lo = r * BINS;

    for (int i = threadIdx.x; i < BINS; i += THREADS) h[i] = 0.0f;
    __syncthreads();

    const int4*   src4 = (const int4*)src;
    const int4*   dst4 = (const int4*)dst;
    const float4* wgt4 = (const float4*)w;

    const int n8 = NEDGES / 8;
    for (int g = c * THREADS + (int)threadIdx.x; g < n8; g += B * THREADS) {
        int4   sa = src4[2 * g], sb = src4[2 * g + 1];
        int4   da = dst4[2 * g], db = dst4[2 * g + 1];
        float4 wa = wgt4[2 * g], wb = wgt4[2 * g + 1];

        int      s[8]  = { sa.x, sa.y, sa.z, sa.w, sb.x, sb.y, sb.z, sb.w };
        unsigned bin[8] = {
            (unsigned)(da.x - lo), (unsigned)(da.y - lo),
            (unsigned)(da.z - lo), (unsigned)(da.w - lo),
            (unsigned)(db.x - lo), (unsigned)(db.y - lo),
            (unsigned)(db.z - lo), (unsigned)(db.w - lo) };
        float    wv[8] = { wa.x, wa.y, wa.z, wa.w, wb.x, wb.y, wb.z, wb.w };

        #pragma unroll
        for (int k = 0; k < 8; ++k) {
            if (bin[k] < (unsigned)BINS) atomicAdd(&h[bin[k]], x[s[k]] * wv[k]);
        }
    }
    __syncthreads();

    float4* outc4 = (float4*)(ws + (size_t)c * NNODES + lo);
    const float4* h4 = (const float4*)h;
    for (int i = threadIdx.x; i < BINS / 4; i += THREADS) outc4[i] = h4[i];
}

// ---------------- Stage 2a: tree reduce 128 -> 16 (in-place) ----------------
__global__ __launch_bounds__(256) void reduceA_kernel(float* __restrict__ ws)
{
    const int NB = NNODES / (256 * 4);
    int g  = blockIdx.x / NB;
    int jb = blockIdx.x % NB;
    int i4 = jb * 256 + (int)threadIdx.x;

    float4* w4 = (float4*)ws;
    const int stride4 = NNODES / 4;

    float4 acc = w4[(size_t)(g * CPG) * stride4 + i4];
    #pragma unroll
    for (int cc = 1; cc < CPG; ++cc) {
        float4 t = w4[(size_t)(g * CPG + cc) * stride4 + i4];
        acc.x += t.x; acc.y += t.y; acc.z += t.z; acc.w += t.w;
    }
    w4[(size_t)(g * CPG) * stride4 + i4] = acc;
}

// ---------------- Stage 2b: 16 partials + bias -> out ----------------
__global__ __launch_bounds__(256) void reduceB_kernel(
    const float* __restrict__ ws,
    const float* __restrict__ bias,
    float*       __restrict__ out)
{
    int i4 = blockIdx.x * 256 + (int)threadIdx.x;
    const float4* w4 = (const float4*)ws;
    const int stride4 = NNODES / 4;

    float4 acc = ((const float4*)bias)[i4];
    #pragma unroll
    for (int g = 0; g < GROUPS; ++g) {
        float4 t = w4[(size_t)(g * CPG) * stride4 + i4];
        acc.x += t.x; acc.y += t.y; acc.z += t.z; acc.w += t.w;
    }
    ((float4*)out)[i4] = acc;
}

// ---------------- Generic fallback reduce (B != NCOPIES) ----------------
__global__ __launch_bounds__(256) void reduce_generic_kernel(
    const float* __restrict__ ws,
    const float* __restrict__ bias,
    float*       __restrict__ out,
    int B)
{
    int i = blockIdx.x * 256 + (int)threadIdx.x;
    float acc = bias[i];
    for (int cc = 0; cc < B; ++cc) acc += ws[(size_t)cc * NNODES + i];
    out[i] = acc;
}

// ---------------- Fallback: global atomics (tiny ws) ----------------
__global__ __launch_bounds__(256) void init_out_kernel(
    const float* __restrict__ bias, float* __restrict__ out)
{
    int i = blockIdx.x * blockDim.x + threadIdx.x;
    if (i < NNODES) out[i] = bias[i];
}

__global__ __launch_bounds__(256) void edge_atomic_kernel(
    const float* __restrict__ x, const float* __restrict__ w,
    const int* __restrict__ src, const int* __restrict__ dst,
    float* __restrict__ out)
{
    const int n4 = NEDGES / 4;
    int tid = blockIdx.x * blockDim.x + threadIdx.x;
    int stride = gridDim.x * blockDim.x;
    for (int i = tid; i < n4; i += stride) {
        int4 s = ((const int4*)src)[i];
        int4 d = ((const int4*)dst)[i];
        float4 ww = ((const float4*)w)[i];
        atomicAdd(&out[d.x], x[s.x] * ww.x);
        atomicAdd(&out[d.y], x[s.y] * ww.y);
        atomicAdd(&out[d.z], x[s.z] * ww.z);
        atomicAdd(&out[d.w], x[s.w] * ww.w);
    }
}

extern "C" void kernel_launch(void* const* d_in, const int* in_sizes, int n_in,
                              void* d_out, int out_size, void* d_ws, size_t ws_size,
                              hipStream_t stream) {
    const float* x    = (const float*)d_in[0];
    const float* w    = (const float*)d_in[1];
    const float* bias = (const float*)d_in[2];
    const int*   src  = (const int*)d_in[3];
    const int*   dst  = (const int*)d_in[4];
    float* out = (float*)d_out;

    const size_t need_two_phase =
        ((size_t)NEDGES + (size_t)NCOPIES * NNODES) * sizeof(float);  // 96 MB

    if (ws_size >= need_two_phase) {
        float* v      = (float*)d_ws;            // 64 MB
        float* copies = v + NEDGES;              // 32 MB
        gather_kernel<<<GBLOCKS, THREADS, 0, stream>>>(x, w, src, v);
        scatter_kernel<<<NCOPIES * RANGES, THREADS, BINS * sizeof(float), stream>>>(
            dst, v, copies, NCOPIES);
        reduceA_kernel<<<GROUPS * (NNODES / 1024), 256, 0, stream>>>(copies);
        reduceB_kernel<<<NNODES / 1024, 256, 0, stream>>>(copies, bias, out);
        return;
    }

    float* ws = (float*)d_ws;
    size_t copies_fit = ws_size / ((size_t)NNODES * sizeof(float));
    int B = (int)(copies_fit < NCOPIES ? copies_fit : NCOPIES);

    if (B >= 1) {
        hist_kernel<<<B * RANGES, THREADS, BINS * sizeof(float), stream>>>(
            x, w, src, dst, ws, B);
        if (B == NCOPIES) {
            reduceA_kernel<<<GROUPS * (NNODES / 1024), 256, 0, stream>>>(ws);
            reduceB_kernel<<<NNODES / 1024, 256, 0, stream>>>(ws, bias, out);
        } else {
            reduce_generic_kernel<<<NNODES / 256, 256, 0, stream>>>(ws, bias, out, B);
        }
    } else {
        init_out_kernel<<<NNODES / 256, 256, 0, stream>>>(bias, out);
        edge_atomic_kernel<<<4096, 256, 0, stream>>>(x, w, src, dst, out);
    }
}